// Round 1
// baseline (204.265 us; speedup 1.0000x reference)
//
#include <hip/hip_runtime.h>

#define NN 8192
#define BB 2
#define TT 1024
#define WW 64
#define HH 256
#define NPB 32
#define DTF (1.0f/24.0f)

__device__ __forceinline__ float sigmoidf_(float v) { return 1.0f / (1.0f + __expf(-v)); }

// ---------------- MLP -> (k, xw) per node ----------------
__global__ __launch_bounds__(256) void mlp_kernel(
    const float* __restrict__ phys,
    const float* __restrict__ w1, const float* __restrict__ b1,
    const float* __restrict__ w2, const float* __restrict__ b2,
    const float* __restrict__ w3, const float* __restrict__ b3,
    float* __restrict__ kxw)
{
    const int n0 = blockIdx.x * NPB;
    const int j  = threadIdx.x;

    __shared__ float s_phys[NPB * 3];
    __shared__ float s_h1[NPB * HH];     // 32 KB
    __shared__ float s_red[4][NPB][2];

    if (j < NPB * 3) s_phys[j] = phys[n0 * 3 + j];
    __syncthreads();

    // layer 1: h1[m][j]
    const float w1v0 = w1[j], w1v1 = w1[HH + j], w1v2 = w1[2 * HH + j], b1v = b1[j];
#pragma unroll
    for (int m = 0; m < NPB; ++m) {
        float h = s_phys[m*3+0] * w1v0 + s_phys[m*3+1] * w1v1 + s_phys[m*3+2] * w1v2 + b1v;
        s_h1[m * HH + j] = fmaxf(h, 0.0f);
    }
    __syncthreads();

    // layer 2: acc[m] = sum_i h1[m][i] * w2[i][j]
    float acc[NPB];
#pragma unroll
    for (int m = 0; m < NPB; ++m) acc[m] = 0.0f;
#pragma unroll 8
    for (int i = 0; i < HH; ++i) {
        const float w2v = w2[i * HH + j];
#pragma unroll
        for (int m = 0; m < NPB; ++m) acc[m] += s_h1[m * HH + i] * w2v;
    }

    const float b2v = b2[j];
    const float w30 = w3[j * 2 + 0], w31 = w3[j * 2 + 1];
    const int wv = j >> 6;

    // layer 3 partials + wave reduction
    for (int m = 0; m < NPB; ++m) {
        const float h2 = fmaxf(acc[m] + b2v, 0.0f);
        float r0 = h2 * w30;
        float r1 = h2 * w31;
#pragma unroll
        for (int o = 32; o >= 1; o >>= 1) {
            r0 += __shfl_xor(r0, o);
            r1 += __shfl_xor(r1, o);
        }
        if ((j & 63) == 0) { s_red[wv][m][0] = r0; s_red[wv][m][1] = r1; }
    }
    __syncthreads();

    if (j < NPB * 2) {
        const int m = j >> 1, d = j & 1;
        float raw = s_red[0][m][d] + s_red[1][m][d] + s_red[2][m][d] + s_red[3][m][d] + b3[d];
        float p;
        if (d == 0) p = sigmoidf_(raw) * 0.25f + 0.005f;          // k
        else        p = sigmoidf_(raw - 3.0f) * 1.2f;             // xw
        kxw[(n0 + m) * 2 + d] = p;
    }
}

// ---------------- per-level routing conv ----------------
// out[n] = irf_n (x) (x[n] + sum_children out[c]), children of n = 4n+1..4n+4
__global__ __launch_bounds__(256) void route_level(
    const float* __restrict__ x,
    const float* __restrict__ kxw,
    float* __restrict__ out,
    int level_start)
{
    const int idx = blockIdx.x;
    const int b   = idx & 1;
    const int n   = level_start + (idx >> 1);
    const int tid = threadIdx.x;

    __shared__ __align__(16) float s_acc[WW + TT];   // A(t) = s_acc[WW + t], prologue zeros
    __shared__ float s_irf[WW];

    // IRF from (k, xw): wave 0 only
    if (tid < WW) {
        const float k  = kxw[n * 2 + 0];
        const float xw = kxw[n * 2 + 1];
        const float t     = tid * DTF;
        const float delay = k * xw;
        const float tau   = fmaxf(k * (1.0f - xw), 0.5f * DTF);
        float h = (t >= delay) ? __expf(-(t - delay) / tau) / tau : 0.0f;
        float s = h;
#pragma unroll
        for (int o = 32; o >= 1; o >>= 1) s += __shfl_xor(s, o);
        s_irf[tid] = h / (s + 1e-8f);
    }

    // zero prologue
    if (tid < WW / 4) *(float4*)&s_acc[tid * 4] = make_float4(0, 0, 0, 0);

    // acc = x + children outs
    const size_t rowb = ((size_t)b * NN + n) * TT;
    float4 v = *(const float4*)&x[rowb + tid * 4];
    const int c0 = 4 * n + 1;
#pragma unroll
    for (int e = 0; e < 4; ++e) {
        const int c = c0 + e;
        if (c < NN) {
            const float4 u = *(const float4*)&out[((size_t)b * NN + c) * TT + tid * 4];
            v.x += u.x; v.y += u.y; v.z += u.z; v.w += u.w;
        }
    }
    *(float4*)&s_acc[WW + tid * 4] = v;
    __syncthreads();

    // irf into registers (uniform broadcast reads)
    float rf[WW];
#pragma unroll
    for (int i = 0; i < WW / 4; ++i) {
        const float4 f = *(const float4*)&s_irf[i * 4];
        rf[i*4+0] = f.x; rf[i*4+1] = f.y; rf[i*4+2] = f.z; rf[i*4+3] = f.w;
    }

    const int base = tid * 4;
    float y[4] = {0.f, 0.f, 0.f, 0.f};
#pragma unroll
    for (int blk = 0; blk < 17; ++blk) {
        const int i0 = blk * 4 - 64;                      // -64 .. 0
        const float4 a = *(const float4*)&s_acc[base + blk * 4];  // A[base+i0 .. base+i0+3]
        const float ae[4] = {a.x, a.y, a.z, a.w};
#pragma unroll
        for (int e = 0; e < 4; ++e) {
            const int i = i0 + e;
#pragma unroll
            for (int jj = 0; jj < 4; ++jj) {
                const int w = jj - i;
                if (w >= 0 && w < WW) y[jj] += rf[w] * ae[e];
            }
        }
    }

    *(float4*)&out[rowb + base] = make_float4(y[0], y[1], y[2], y[3]);
}

extern "C" void kernel_launch(void* const* d_in, const int* in_sizes, int n_in,
                              void* d_out, int out_size, void* d_ws, size_t ws_size,
                              hipStream_t stream) {
    const float* x    = (const float*)d_in[0];
    const float* phys = (const float*)d_in[1];
    const float* w1   = (const float*)d_in[2];
    const float* b1   = (const float*)d_in[3];
    const float* w2   = (const float*)d_in[4];
    const float* b2   = (const float*)d_in[5];
    const float* w3   = (const float*)d_in[6];
    const float* b3   = (const float*)d_in[7];
    // d_in[8] = parent, d_in[9] = depth: tree structure is fixed (4-ary heap order)

    float* out = (float*)d_out;
    float* kxw = (float*)d_ws;   // N*2 floats = 64 KB

    mlp_kernel<<<NN / NPB, 256, 0, stream>>>(phys, w1, b1, w2, b2, w3, b3, kxw);

    static const int starts[9] = {0, 1, 5, 21, 85, 341, 1365, 5461, 8192};
    for (int d = 7; d >= 0; --d) {
        const int s   = starts[d];
        const int cnt = starts[d + 1] - s;
        route_level<<<cnt * 2, 256, 0, stream>>>(x, kxw, out, s);
    }
}

// Round 3
// 144.605 us; speedup vs baseline: 1.4126x; 1.4126x over previous
//
#include <hip/hip_runtime.h>

#define NN 8192
#define BB 2
#define TT 1024
#define WW 64
#define HH 256
#define NPB 8
#define DTF (1.0f/24.0f)

__device__ __forceinline__ float sigmoidf_(float v) { return 1.0f / (1.0f + __expf(-v)); }

// ---------------- MLP -> (k, xw) per node ----------------
// NPB=8 nodes/block, 1024 blocks -> 4 blocks/CU, latency hidden.
__global__ __launch_bounds__(256) void mlp_kernel(
    const float* __restrict__ phys,
    const float* __restrict__ w1, const float* __restrict__ b1,
    const float* __restrict__ w2, const float* __restrict__ b2,
    const float* __restrict__ w3, const float* __restrict__ b3,
    float* __restrict__ kxw)
{
    const int n0 = blockIdx.x * NPB;
    const int j  = threadIdx.x;

    __shared__ float s_phys[NPB * 3];
    __shared__ __align__(16) float s_h1[NPB * HH];   // 8 KB
    __shared__ float s_red[4][NPB][2];

    if (j < NPB * 3) s_phys[j] = phys[n0 * 3 + j];
    __syncthreads();

    // layer 1: h1[m][j]
    const float w1v0 = w1[j], w1v1 = w1[HH + j], w1v2 = w1[2 * HH + j], b1v = b1[j];
#pragma unroll
    for (int m = 0; m < NPB; ++m) {
        float h = s_phys[m*3+0] * w1v0 + s_phys[m*3+1] * w1v1 + s_phys[m*3+2] * w1v2 + b1v;
        s_h1[m * HH + j] = fmaxf(h, 0.0f);
    }
    __syncthreads();

    // layer 2: acc[m] = sum_i h1[m][i] * w2[i][j], i vectorized by 4 (b128 broadcast)
    float acc[NPB];
#pragma unroll
    for (int m = 0; m < NPB; ++m) acc[m] = 0.0f;

#pragma unroll 4
    for (int i4 = 0; i4 < HH / 4; ++i4) {
        const int i = i4 * 4;
        const float wv0 = w2[(i + 0) * HH + j];
        const float wv1 = w2[(i + 1) * HH + j];
        const float wv2 = w2[(i + 2) * HH + j];
        const float wv3 = w2[(i + 3) * HH + j];
#pragma unroll
        for (int m = 0; m < NPB; ++m) {
            const float4 h4 = *(const float4*)&s_h1[m * HH + i];
            acc[m] += h4.x * wv0 + h4.y * wv1 + h4.z * wv2 + h4.w * wv3;
        }
    }

    const float b2v = b2[j];
    const float w30 = w3[j * 2 + 0], w31 = w3[j * 2 + 1];
    const int wv = j >> 6;

    // layer 3 partials + wave reduction
#pragma unroll
    for (int m = 0; m < NPB; ++m) {
        const float h2 = fmaxf(acc[m] + b2v, 0.0f);
        float r0 = h2 * w30;
        float r1 = h2 * w31;
#pragma unroll
        for (int o = 32; o >= 1; o >>= 1) {
            r0 += __shfl_xor(r0, o);
            r1 += __shfl_xor(r1, o);
        }
        if ((j & 63) == 0) { s_red[wv][m][0] = r0; s_red[wv][m][1] = r1; }
    }
    __syncthreads();

    if (j < NPB * 2) {
        const int m = j >> 1, d = j & 1;
        float raw = s_red[0][m][d] + s_red[1][m][d] + s_red[2][m][d] + s_red[3][m][d] + b3[d];
        float p;
        if (d == 0) p = sigmoidf_(raw) * 0.25f + 0.005f;          // k
        else        p = sigmoidf_(raw - 3.0f) * 1.2f;             // xw
        kxw[(n0 + m) * 2 + d] = p;
    }
}

// ---------------- per-level routing conv ----------------
// out[n] = irf_n (x) (x[n] + sum_children out[c]), children of n = 4n+1..4n+4
__global__ __launch_bounds__(256) void route_level(
    const float* __restrict__ x,
    const float* __restrict__ kxw,
    float* __restrict__ out,
    int level_start)
{
    const int idx = blockIdx.x;
    const int b   = idx & 1;
    const int n   = level_start + (idx >> 1);
    const int tid = threadIdx.x;

    __shared__ __align__(16) float s_acc[WW + TT];   // A(t) = s_acc[WW + t], prologue zeros
    __shared__ float s_irf[WW];

    // issue global loads FIRST so VMEM latency overlaps the IRF math.
    // NOTE: per-child bounds check — node 2047 has children 8189..8192,
    // the 4th is OOB (this was round 2's crash).
    const size_t rowb = ((size_t)b * NN + n) * TT;
    float4 v = *(const float4*)&x[rowb + tid * 4];
    const int c0 = 4 * n + 1;
    float4 u[4];
    bool cin[4];
#pragma unroll
    for (int e = 0; e < 4; ++e) {
        const int c = c0 + e;
        cin[e] = (c < NN);
        if (cin[e]) u[e] = *(const float4*)&out[((size_t)b * NN + c) * TT + tid * 4];
    }

    // IRF from (k, xw): wave 0 only
    if (tid < WW) {
        const float k  = kxw[n * 2 + 0];
        const float xw = kxw[n * 2 + 1];
        const float t     = tid * DTF;
        const float delay = k * xw;
        const float tau   = fmaxf(k * (1.0f - xw), 0.5f * DTF);
        float h = (t >= delay) ? __expf(-(t - delay) / tau) / tau : 0.0f;
        float s = h;
#pragma unroll
        for (int o = 32; o >= 1; o >>= 1) s += __shfl_xor(s, o);
        s_irf[tid] = h / (s + 1e-8f);
    }

    // zero prologue
    if (tid < WW / 4) *(float4*)&s_acc[tid * 4] = make_float4(0, 0, 0, 0);

#pragma unroll
    for (int e = 0; e < 4; ++e) {
        if (cin[e]) {
            v.x += u[e].x; v.y += u[e].y; v.z += u[e].z; v.w += u[e].w;
        }
    }
    *(float4*)&s_acc[WW + tid * 4] = v;
    __syncthreads();

    // irf into registers (uniform broadcast reads)
    float rf[WW];
#pragma unroll
    for (int i = 0; i < WW / 4; ++i) {
        const float4 f = *(const float4*)&s_irf[i * 4];
        rf[i*4+0] = f.x; rf[i*4+1] = f.y; rf[i*4+2] = f.z; rf[i*4+3] = f.w;
    }

    const int base = tid * 4;
    float y[4] = {0.f, 0.f, 0.f, 0.f};
#pragma unroll
    for (int blk = 0; blk < 17; ++blk) {
        const int i0 = blk * 4 - 64;                      // -64 .. 0
        const float4 a = *(const float4*)&s_acc[base + blk * 4];  // A[base+i0 .. base+i0+3]
        const float ae[4] = {a.x, a.y, a.z, a.w};
#pragma unroll
        for (int e = 0; e < 4; ++e) {
            const int i = i0 + e;
#pragma unroll
            for (int jj = 0; jj < 4; ++jj) {
                const int w = jj - i;
                if (w >= 0 && w < WW) y[jj] += rf[w] * ae[e];
            }
        }
    }

    *(float4*)&out[rowb + base] = make_float4(y[0], y[1], y[2], y[3]);
}

extern "C" void kernel_launch(void* const* d_in, const int* in_sizes, int n_in,
                              void* d_out, int out_size, void* d_ws, size_t ws_size,
                              hipStream_t stream) {
    const float* x    = (const float*)d_in[0];
    const float* phys = (const float*)d_in[1];
    const float* w1   = (const float*)d_in[2];
    const float* b1   = (const float*)d_in[3];
    const float* w2   = (const float*)d_in[4];
    const float* b2   = (const float*)d_in[5];
    const float* w3   = (const float*)d_in[6];
    const float* b3   = (const float*)d_in[7];
    // d_in[8] = parent, d_in[9] = depth: tree structure is fixed (4-ary heap order)

    float* out = (float*)d_out;
    float* kxw = (float*)d_ws;   // N*2 floats = 64 KB

    mlp_kernel<<<NN / NPB, 256, 0, stream>>>(phys, w1, b1, w2, b2, w3, b3, kxw);

    static const int starts[9] = {0, 1, 5, 21, 85, 341, 1365, 5461, 8192};
    for (int d = 7; d >= 0; --d) {
        const int s   = starts[d];
        const int cnt = starts[d + 1] - s;
        route_level<<<cnt * 2, 256, 0, stream>>>(x, kxw, out, s);
    }
}